// Round 12
// baseline (171.220 us; speedup 1.0000x reference)
//
#include <hip/hip_runtime.h>

typedef __attribute__((ext_vector_type(8))) short frag8;     // 8 bf16 = 4 VGPRs
typedef __attribute__((ext_vector_type(4))) float f4;
typedef __attribute__((ext_vector_type(4), aligned(8))) float f4a;  // 8B-aligned loads
typedef __attribute__((ext_vector_type(4))) unsigned int u4;
typedef __attribute__((ext_vector_type(2))) unsigned int u2;
typedef __attribute__((ext_vector_type(2))) float f2;

namespace {
constexpr int T_STEPS = 25;
constexpr int IN_F    = 14;
constexpr int H       = 24;
constexpr int NSTEP   = 13;
constexpr int STEP_B  = 512;               // 16 elems x 8 words x 4 B
constexpr int WAVE_REGION = 14 * STEP_B;   // 13 steps + 1 pad slot (prefetch overrun)
// Structure = R8 (known-good, 55.1 us) + R9's two-phase prefill (known-good).
// The 2-chains-per-wave variants (R10/R11) NaN'd twice and are abandoned.
//
// M=96 layout (6 tiles of 16 rows):
//   tile t<4, row m -> gate t, unit m      (vector units 0..15)
//   tile 4, row m (r=m&3, qq=m>>2) -> gate r>>1 (i/f),   unit (r&1?20:16)+qq
//   tile 5, row m                  -> gate 2+(r>>1) (g/o), unit (r&1?20:16)+qq
// C/D lane (q=lane>>4, col=lane&15):
//   acc[0..3][r] = gate t of unit 4q+r ; acc[4]={i,i,f,f}, acc[5]={g,g,o,o}
//   of units {16+q,20+q} (paired scalar-unit layout).
//
// MERGED 2-MFMA k-map (x folded into the Wh MFMAs' free slots):
// Both MFMAs m=0,1 share the Wh unit map at j=0..5 of each k-group q':
//   j<4 -> unit 4q'+j ; j=4 -> 16+q' ; j=5 -> 20+q'
//   (m=0 multiplies h_hi, m=1 multiplies h_lo; identical Wh weights)
// Slots j=6,7 carry Wx columns (x as single rne-bf16):
//   m=0: features {4q'+0, 4q'+1}
//   m=1, q'<3: features {4q'+2, 4q'+3}
//   m=1, q'=3: {bias_hi, bias_lo}, B supplies {1.0, 1.0}
//
// LDS x staging, LINEAR layout: step t, pair p -> byte t*512 + p*8; lane l
// reads its pair at l*8 (one ds_read_b64 per step). Prefill: lane l stages
// chunk c=l&3 of elem e=l>>2; TWO-PHASE: 13 independent 16B loads into regs
// (one exposed latency window), then 13 cvt_pk + ds_write_b64.
//
// d_ws: shorts [0..12288): frags ((dir*2+m)*6+tile)*64+lane, 8 shorts.
//   Pre-scaled per gate: i,f,o rows * (-log2e), g rows * (2*log2e).
// Gate math: packed fp32; running c PRE-SCALED by 2*log2e (EC = exp2(c')).
constexpr float LOG2E    = 1.4426950408889634f;
constexpr float TWOLOG2E = 2.8853900817779268f;
}

#if __has_builtin(__builtin_amdgcn_exp2f)
#define EXP2F(v) __builtin_amdgcn_exp2f(v)
#else
#define EXP2F(v) __expf(0.6931471805599453f * (v))
#endif

__device__ __forceinline__ unsigned short bf16_rne(float f) {
    unsigned int u = __float_as_uint(f);
    u += 0x7fff + ((u >> 16) & 1);
    return (unsigned short)(u >> 16);
}
__device__ __forceinline__ float bf16_to_f(unsigned short s) {
    return __uint_as_float(((unsigned int)s) << 16);
}
__device__ __forceinline__ float fast_rcp(float x) { return __builtin_amdgcn_rcpf(x); }

// ---- packed fp32 VALU (VOP3P) helpers ----
__device__ __forceinline__ f2 pk_add(f2 a, f2 b) {
    f2 d; asm("v_pk_add_f32 %0, %1, %2" : "=v"(d) : "v"(a), "v"(b)); return d;
}
__device__ __forceinline__ f2 pk_mul(f2 a, f2 b) {
    f2 d; asm("v_pk_mul_f32 %0, %1, %2" : "=v"(d) : "v"(a), "v"(b)); return d;
}
__device__ __forceinline__ f2 pk_fma(f2 a, f2 b, f2 c) {
    f2 d; asm("v_pk_fma_f32 %0, %1, %2, %3" : "=v"(d) : "v"(a), "v"(b), "v"(c)); return d;
}

__global__ void pack_mfma(const float* __restrict__ wif, const float* __restrict__ whf,
                          const float* __restrict__ bif, const float* __restrict__ bhf,
                          const float* __restrict__ wib, const float* __restrict__ whb,
                          const float* __restrict__ bib, const float* __restrict__ bhb,
                          unsigned short* __restrict__ ws)
{
    const int gid = blockIdx.x * 256 + threadIdx.x;
    if (gid >= 1536) return;                 // 2 dir * 2 mfma-sets * 6 tiles * 64 lanes
    const int lane = gid & 63;
    const int tile = (gid >> 6) % 6;
    const int m    = (gid / 384) & 1;        // MFMA index within the step
    const int dir  = gid / 768;
    const int rm = lane & 15, qA = lane >> 4;   // A-frag: row-in-tile, k = qA*8+j
    int g, u_row;
    if (tile < 4) { g = tile; u_row = rm; }
    else {
        const int r = rm & 3, qq = rm >> 2;   // paired scalar-unit layout (see header)
        g = (tile == 4 ? 0 : 2) + (r >> 1);
        u_row = ((r & 1) ? 20 : 16) + qq;
    }
    const float* Wx = dir ? wib : wif;
    const float* Wh = dir ? whb : whf;
    const float* bi = dir ? bib : bif;
    const float* bh = dir ? bhb : bhf;
    const int rowW = g * 24 + u_row;         // original weight row
    const float scale = (g == 2) ? TWOLOG2E : -LOG2E;   // g-gate vs i,f,o
    unsigned short vals[8];
    #pragma unroll
    for (int j = 0; j < 8; ++j) {
        unsigned short o;
        if (j < 6) {
            // shared Wh unit map (both MFMAs; m=0 hits h_hi, m=1 hits h_lo)
            const int uh = (j < 4) ? (qA * 4 + j) : ((j == 4 ? 16 : 20) + qA);
            o = bf16_rne(scale * Wh[rowW * H + uh]);
        } else {
            const int jj = j - 6;
            if (m == 0) {
                o = bf16_rne(scale * Wx[rowW * IN_F + 4 * qA + jj]);
            } else if (qA < 3) {
                o = bf16_rne(scale * Wx[rowW * IN_F + 4 * qA + 2 + jj]);
            } else {
                const float b = scale * (bi[rowW] + bh[rowW]);
                const unsigned short hi = bf16_rne(b);
                o = (jj == 0) ? hi : bf16_rne(b - bf16_to_f(hi));
            }
        }
        vals[j] = o;
    }
    unsigned short* d = ws + (size_t)gid * 8;
    #pragma unroll
    for (int j = 0; j < 8; ++j) d[j] = vals[j];
}

// One packed pair (2 units) of the LSTM nonlinear update, pre-scaled accs:
// i,f,o hold -a*log2e; g holds 2a*log2e; cvs holds 2*log2e*c (pre-scaled).
// c' = (c*P + (eg-1)(1+ef)) / ((1+ef)*P),  P = (1+ei)(1+eg)
// h  = (ec-1)/((1+eo)(1+ec)),  ec = exp2(cvs')
// rcp paired across the two units: r = rcp(d0*d1); 1/d0 = r*d1, 1/d1 = r*d0.
__device__ __forceinline__ void gates_pair(float ai0, float ai1, float af0, float af1,
                                           float ag0, float ag1, float ao0, float ao1,
                                           f2& cvs, f2& Hp,
                                           f2 ONE, f2 NEGONE, f2 T2L, f2 NT2L)
{
    f2 ei, ef, eg, eo;
    ei.x = EXP2F(ai0); ei.y = EXP2F(ai1);
    ef.x = EXP2F(af0); ef.y = EXP2F(af1);
    eg.x = EXP2F(ag0); eg.y = EXP2F(ag1);
    eo.x = EXP2F(ao0); eo.y = EXP2F(ao1);
    const f2 efp1 = pk_add(ef, ONE);
    const f2 P    = pk_mul(pk_add(ei, ONE), pk_add(eg, ONE));
    const f2 Df   = pk_mul(P, efp1);
    const float r = fast_rcp(Df.x * Df.y);
    f2 Rf; Rf.x = r * Df.y; Rf.y = r * Df.x;
    const f2 X = pk_mul(pk_fma(eg, T2L, NT2L), efp1);   // 2L*(eg-1)*(1+ef)
    cvs = pk_mul(pk_fma(cvs, P, X), Rf);                // pre-scaled c
    f2 ec; ec.x = EXP2F(cvs.x); ec.y = EXP2F(cvs.y);
    const f2 Do = pk_mul(pk_add(eo, ONE), pk_add(ec, ONE));
    const float r2 = fast_rcp(Do.x * Do.y);
    f2 Ro; Ro.x = r2 * Do.y; Ro.y = r2 * Do.x;
    Hp = pk_mul(pk_add(ec, NEGONE), Ro);
}

__device__ __forceinline__ unsigned int perm_hi16(float a_hi, float a_lo) {
    // pack {hi16(a_lo), hi16(a_hi)} with a_lo in the low half (j-even slot)
    return __builtin_amdgcn_perm(__float_as_uint(a_hi), __float_as_uint(a_lo), 0x07060302u);
}

__global__ __launch_bounds__(128, 4)
void bilstm_mfma(const float* __restrict__ x, const unsigned short* __restrict__ wpk,
                 const float* __restrict__ head_w, const float* __restrict__ head_b,
                 float* __restrict__ out, int B)
{
    // per-wave x staging region (pre-packed bf16 pairs); h-exchange reuses it
    __align__(16) __shared__ unsigned char arena[2 * WAVE_REGION];   // 14 KiB

    const int tid  = threadIdx.x;
    const int wave = __builtin_amdgcn_readfirstlane(tid >> 6);   // 0 = fwd, 1 = bwd
    const int lane = tid & 63;
    const int q    = lane >> 4;
    const int col  = lane & 15;
    const int b0   = blockIdx.x * 16;

    // resident weight A-fragments: 2 MFMA-sets x 6 tiles = 48 VGPRs
    frag8 Aw[2][6];
    #pragma unroll
    for (int m = 0; m < 2; ++m)
        #pragma unroll
        for (int t = 0; t < 6; ++t)
            Aw[m][t] = ((const frag8*)wpk)[((wave * 2 + m) * 6 + t) * 64 + lane];

    unsigned char* xbase = arena + wave * WAVE_REGION;

    // ---- prefill, TWO-PHASE (R9 structure): 13 independent loads -> regs,
    // then cvt_pk + ds_write. One exposed HBM/L3 latency window instead of ~4.
    // lane l -> chunk c = l&3 of elem e = l>>2; 4 lanes/row read contiguous 16B.
    // c<3: features 4c..4c+3 at byte c*16 ; c==3: load byte 40 (f10..f13),
    // use .z,.w (f12,f13), pair word = bf16{1,1} for the bias A-slots.
    {
        const int c  = lane & 3;
        const int e  = lane >> 2;
        const bool c3 = (c == 3);
        const int ldo = c3 ? 40 : c * 16;
        const int woff = (c * 16 + e) * 8;       // pair-index p = c*16+e (linear)
        const int dstep = wave ? -(IN_F * 4) : (IN_F * 4);
        const char* xcol = (const char*)x
                         + ((size_t)(b0 + e) * T_STEPS + (wave ? T_STEPS - 1 : 0))
                           * (IN_F * 4) + ldo;
        f4a v[NSTEP];
        #pragma unroll
        for (int t = 0; t < NSTEP; ++t)
            v[t] = *(const f4a*)(xcol + t * dstep);   // 13 independent 16B loads
        #pragma unroll
        for (int t = 0; t < NSTEP; ++t) {
            unsigned int p0, p1;
            asm("v_cvt_pk_bf16_f32 %0, %1, %2" : "=v"(p0) : "v"(v[t].x), "v"(v[t].y));
            asm("v_cvt_pk_bf16_f32 %0, %1, %2" : "=v"(p1) : "v"(v[t].z), "v"(v[t].w));
            const unsigned int wa = c3 ? p1 : p0;
            const unsigned int wb = c3 ? 0x3F803F80u : p1;
            *(u2*)(xbase + t * STEP_B + woff) = (u2){wa, wb};
        }
    }
    // same-wave DS ops are in-order: no barrier needed before own reads

    const int xoff = lane * 8;                 // lane's x pair per step

    // loop-invariant packed constants
    const f2 ONE    = {1.0f, 1.0f};
    const f2 NEGONE = {-1.0f, -1.0f};
    const f2 T2L    = {TWOLOG2E, TWOLOG2E};
    const f2 NT2L   = {-TWOLOG2E, -TWOLOG2E};

    // state: pre-scaled c (2log2e*c) per pair; fp32 h per pair (for head+pack)
    f2 cvl = {0.f, 0.f}, cvh = {0.f, 0.f}, cvs = {0.f, 0.f};
    f2 Hlo, Hhi, Hs;                       // h of units {4q,4q+1},{4q+2,4q+3},{16+q,20+q}
    unsigned int uh0 = 0, uh1 = 0, uh2 = 0;   // h_hi words (step 0: h = 0)
    unsigned int ul0 = 0, ul1 = 0, ul2 = 0;   // h_lo words
    const f4 zc = {0.f, 0.f, 0.f, 0.f};

    u2 xw = *(const u2*)(xbase + xoff);        // step-0 x pair

    // ---- steps 0..12: uniform 2-MFMA recurrence, x pair prefetched 1 step ----
    #pragma unroll 1
    for (int s = 0; s < NSTEP; ++s) {
        const u2 xn = *(const u2*)(xbase + (s + 1) * STEP_B + xoff);  // slot 13 = pad
        const frag8 B0 = __builtin_bit_cast(frag8, (u4){uh0, uh1, uh2, xw.x});
        const frag8 B1 = __builtin_bit_cast(frag8, (u4){ul0, ul1, ul2, xw.y});
        f4 acc[6];
        #pragma unroll
        for (int t = 0; t < 6; ++t) {
            acc[t] = __builtin_amdgcn_mfma_f32_16x16x32_bf16(Aw[0][t], B0, zc,     0, 0, 0);
            acc[t] = __builtin_amdgcn_mfma_f32_16x16x32_bf16(Aw[1][t], B1, acc[t], 0, 0, 0);
        }
        // three packed pairs: units {4q,4q+1}, {4q+2,4q+3}, {16+q,20+q}
        gates_pair(acc[0][0], acc[0][1], acc[1][0], acc[1][1],
                   acc[2][0], acc[2][1], acc[3][0], acc[3][1],
                   cvl, Hlo, ONE, NEGONE, T2L, NT2L);
        gates_pair(acc[0][2], acc[0][3], acc[1][2], acc[1][3],
                   acc[2][2], acc[2][3], acc[3][2], acc[3][3],
                   cvh, Hhi, ONE, NEGONE, T2L, NT2L);
        gates_pair(acc[4][0], acc[4][1], acc[4][2], acc[4][3],
                   acc[5][0], acc[5][1], acc[5][2], acc[5][3],
                   cvs, Hs, ONE, NEGONE, T2L, NT2L);

        // pack h -> B-frag words: hi = trunc16(h), lo = h - hi (hi16 via perm)
        f2 Tl, Th, Ts;
        Tl.x = __uint_as_float(__float_as_uint(Hlo.x) & 0xFFFF0000u);
        Tl.y = __uint_as_float(__float_as_uint(Hlo.y) & 0xFFFF0000u);
        Th.x = __uint_as_float(__float_as_uint(Hhi.x) & 0xFFFF0000u);
        Th.y = __uint_as_float(__float_as_uint(Hhi.y) & 0xFFFF0000u);
        Ts.x = __uint_as_float(__float_as_uint(Hs.x) & 0xFFFF0000u);
        Ts.y = __uint_as_float(__float_as_uint(Hs.y) & 0xFFFF0000u);
        const f2 Ll = pk_fma(Tl, NEGONE, Hlo);
        const f2 Lh = pk_fma(Th, NEGONE, Hhi);
        const f2 Ls = pk_fma(Ts, NEGONE, Hs);
        uh0 = perm_hi16(Hlo.y, Hlo.x); uh1 = perm_hi16(Hhi.y, Hhi.x);
        uh2 = perm_hi16(Hs.y, Hs.x);
        ul0 = perm_hi16(Ll.y, Ll.x);   ul1 = perm_hi16(Lh.y, Lh.x);
        ul2 = perm_hi16(Ls.y, Ls.x);

        xw = xn;
    }

    // final h (fp32) -> own wave region (x staging is dead; in-order DS per wave)
    *(f2*)(xbase + col * 96 + q * 16)     = Hlo;              // units 4q, 4q+1
    *(f2*)(xbase + col * 96 + q * 16 + 8) = Hhi;              // units 4q+2, 4q+3
    *(float*)(xbase + col * 96 + 64 + q * 4) = Hs.x;          // unit 16+q
    *(float*)(xbase + col * 96 + 80 + q * 4) = Hs.y;          // unit 20+q

    __syncthreads();   // only cross-wave point: head reads both directions' h

    if (tid < 64) {
        const int e = tid >> 2, cls = tid & 3;
        float acc = head_b[cls];
        const float* hf = (const float*)(arena + e * 96);                  // fwd
        const float* hb = (const float*)(arena + WAVE_REGION + e * 96);    // bwd
        #pragma unroll
        for (int u = 0; u < H; ++u)
            acc += hf[u] * head_w[cls * 2 * H + u] + hb[u] * head_w[cls * 2 * H + H + u];
        out[(size_t)b0 * 4 + tid] = acc;
    }
}

extern "C" void kernel_launch(void* const* d_in, const int* in_sizes, int n_in,
                              void* d_out, int out_size, void* d_ws, size_t ws_size,
                              hipStream_t stream)
{
    const float* x      = (const float*)d_in[0];
    const float* w_ih_f = (const float*)d_in[1];
    const float* w_hh_f = (const float*)d_in[2];
    const float* b_ih_f = (const float*)d_in[3];
    const float* b_hh_f = (const float*)d_in[4];
    const float* w_ih_b = (const float*)d_in[5];
    const float* w_hh_b = (const float*)d_in[6];
    const float* b_ih_b = (const float*)d_in[7];
    const float* b_hh_b = (const float*)d_in[8];
    const float* head_w = (const float*)d_in[9];
    const float* head_b = (const float*)d_in[10];
    float* out = (float*)d_out;
    unsigned short* ws = (unsigned short*)d_ws;

    const int B = in_sizes[0] / (T_STEPS * IN_F);

    hipLaunchKernelGGL(pack_mfma, dim3(6), dim3(256), 0, stream,
                       w_ih_f, w_hh_f, b_ih_f, b_hh_f,
                       w_ih_b, w_hh_b, b_ih_b, b_hh_b, ws);
    hipLaunchKernelGGL(bilstm_mfma, dim3((B + 15) / 16), dim3(128), 0, stream,
                       x, ws, head_w, head_b, out, B);
}